// Round 1
// 252.793 us; speedup vs baseline: 1.2139x; 1.2139x over previous
//
#include <hip/hip_runtime.h>

// StyleBlock B=8, C=512, H=W=64, K=3 — bf16 MFMA implicit-GEMM conv, round 6.
// vs round 5: conv_kernel only —
//  (1) wave decomposition: each of the 4 waves owns a DISTINCT 64-o slice and
//      computes the full 2x64-px tile (p=4,q=8). Previously the two wc waves
//      read identical A-fragments -> A-side L2 traffic per block halved
//      (4.6 MB -> 2.3 MB). LDS B-reads double but stay under the MFMA floor.
//  (2) XCD swizzle now binds G (the 256-o half of wfrag) to XCD parity
//      (G = lin&1 under round-robin XCD = lin%8): each XCD's L2 only sees its
//      2.36 MB wfrag half, which FITS the 4 MB per-XCD L2 (the full 4.7 MB
//      previously thrashed to Infinity Cache). A-stream becomes L2-resident.
//  (3) s_setprio(1) around each MFMA cluster.

#define CC 512
#define BB 8
#define HWSZ 4096

#define C_STYLE 0.04419417382415922f   // 1/sqrt(512)
#define C_CONV  0.014731391274719739f  // 1/sqrt(512*9)

typedef __attribute__((ext_vector_type(8))) short bf16x8;
typedef __attribute__((ext_vector_type(4))) float f32x4;

static __device__ __forceinline__ short f2bf(float f) {
  unsigned u = __float_as_uint(f);
  unsigned r = (u + 0x7fffu + ((u >> 16) & 1u)) >> 16;  // RNE
  return (short)r;
}

static __device__ __forceinline__ void load_lds_16(const void* g, void* l) {
  __builtin_amdgcn_global_load_lds(
      (const __attribute__((address_space(1))) unsigned int*)g,
      (__attribute__((address_space(3))) unsigned int*)l, 16, 0, 0);
}

// ------------- wprep: cw fp32 -> bf16 A-frags + wsq (fused) -------------
// wfrag idx: (((t*16 + ib32)*32 + ob)*64 + lane)*8 + j
//   o = ob*16 + (lane&15), i = ib32*32 + ((lane>>4)&3)*8 + j
__global__ void wprep_kernel(const float* __restrict__ cw,
                             short* __restrict__ wfrag,
                             float* __restrict__ wsq) {
  int t0 = blockIdx.x * blockDim.x + threadIdx.x;  // [0, 512*512) = o*512+i
  int o = t0 >> 9;
  int i = t0 & 511;
  int ib32 = i >> 5;
  int ob = o >> 4;
  int lane = (o & 15) + (((i >> 3) & 3) << 4);
  int j = i & 7;
  const float* p = cw + (size_t)t0 * 9;
  float s = 0.f;
#pragma unroll
  for (int t = 0; t < 9; ++t) {
    float v = p[t];
    s = fmaf(v, v, s);
    wfrag[((((size_t)t * 16 + ib32) * 32 + ob) * 64 + lane) * 8 + j] = f2bf(v);
  }
  wsq[t0] = s;
}

// ---------------- style -> alpha (wave per (b,j)) ----------------
__global__ void style_alpha_kernel(const float* __restrict__ w,
                                   const float* __restrict__ sw,
                                   const float* __restrict__ sbias,
                                   float* __restrict__ alpha) {
  int wv = (blockIdx.x * blockDim.x + threadIdx.x) >> 6;  // [0, B*C)
  int lane = threadIdx.x & 63;
  int b = wv >> 9;
  int j = wv & 511;
  float acc = 0.f;
  const float* wr = w + b * CC;
  const float* sr = sw + (size_t)j * CC;
#pragma unroll
  for (int k = 0; k < CC; k += 64) acc = fmaf(wr[k + lane], sr[k + lane], acc);
#pragma unroll
  for (int off = 32; off > 0; off >>= 1) acc += __shfl_down(acc, off);
  if (lane == 0) alpha[wv] = C_CONV * fmaf(C_STYLE, acc, sbias[j]);
}

// ---------------- demod (wave per (b,o)) ----------------
__global__ void demod_kernel(const float* __restrict__ alpha,
                             const float* __restrict__ wsq,
                             float* __restrict__ demod) {
  int wv = (blockIdx.x * blockDim.x + threadIdx.x) >> 6;  // [0, B*C)
  int lane = threadIdx.x & 63;
  int b = wv >> 9;
  int o = wv & 511;
  const float* ar = alpha + b * CC;
  const float* qr = wsq + (size_t)o * CC;
  float s = 0.f;
#pragma unroll
  for (int i = 0; i < CC; i += 64) {
    float a = ar[i + lane];
    s = fmaf(a * a, qr[i + lane], s);
  }
#pragma unroll
  for (int off = 32; off > 0; off >>= 1) s += __shfl_down(s, off);
  if (lane == 0) {
    s += 1e-8f;
    float r = rsqrtf(s);
    r = r * fmaf(-0.5f * s * r, r, 1.5f);
    demod[wv] = r;
  }
}

// ------- xprep: xT[b][ic][py 66][px 66][8i] = bf16(alpha*x), halo zero -----
// grid (66 py, 16 icg, 8 b), block 256: icq = tid>>6, px = tid&63
__global__ void xprep_kernel(const float* __restrict__ x,
                             const float* __restrict__ alpha,
                             short* __restrict__ xT) {
  const int py = blockIdx.x;               // 0..65
  const int ic = blockIdx.y * 4 + (threadIdx.x >> 6);
  const int b = blockIdx.z;
  const int px = threadIdx.x & 63;
  bf16x8 v = (bf16x8){0, 0, 0, 0, 0, 0, 0, 0};
  if (py >= 1 && py <= 64) {
    const float* xp = x + (((size_t)b * CC + ic * 8) * HWSZ + (py - 1) * 64 + px);
    const float* al = alpha + b * CC + ic * 8;
#pragma unroll
    for (int j = 0; j < 8; ++j) v[j] = f2bf(xp[(size_t)j * HWSZ] * al[j]);
  }
  short* row = xT + (((size_t)(b * 64 + ic) * 66 + py) * 66) * 8;
  *(bf16x8*)(row + (px + 1) * 8) = v;
  bf16x8 z = (bf16x8){0, 0, 0, 0, 0, 0, 0, 0};
  if (px == 0) *(bf16x8*)(row) = z;
  if (px == 63) *(bf16x8*)(row + 65 * 8) = z;
}

// ---------------- conv: MFMA implicit GEMM ----------------
// grid 512 blocks, 256 threads = 4 waves, each wave owns 64 o x 128 px.
// Block tile: 256 o x (2 rows x 64 px). K-loop: 8 ibs of 64 i.
// LDS: chunks [kc 8][r 4][c 66] x 16B = 33792 B (2112 chunks).
// Swizzle: XCD = lin%8 (hw round-robin); G = XCD parity so each XCD's L2
// only caches one 2.36 MB half of wfrag (L2-resident A stream).
#define NCHUNK 2112
__global__ __launch_bounds__(256, 2) void conv_kernel(
    const short* __restrict__ xT,
    const short* __restrict__ wfrag,
    const float* __restrict__ noise,
    const float* __restrict__ bias,
    const float* __restrict__ scale_noise,
    const float* __restrict__ demod,
    float* __restrict__ out) {
  __shared__ __align__(16) short xs[NCHUNK * 8];

  const int lin = blockIdx.x + 32 * blockIdx.y + 64 * blockIdx.z;
  const int xcd = lin & 7;                  // assumed hw XCD = lin % 8
  const int j = lin >> 3;                   // 0..63, per-XCD block sequence
  const int G = xcd & 1;                    // 256-o group, constant per XCD
  const int b = (xcd >> 1) + 4 * (j & 1);   // 2 b-values per XCD
  const int y0 = (j >> 1) * 2;              // first output row (0..62 even)
  const int tid = threadIdx.x;
  const int lane = tid & 63;
  const int wave = tid >> 6;                // owns o in [G*256+wave*64, +64)
  const int n = lane & 15;
  const int quad = lane >> 4;

  f32x4 acc[4][8];                          // [p (16-o frag)][q (row*4+colblk)]
#pragma unroll
  for (int p = 0; p < 4; ++p)
#pragma unroll
    for (int q = 0; q < 8; ++q) acc[p][q] = (f32x4){0.f, 0.f, 0.f, 0.f};

  // staging descriptors: chunk cid = (kc*4 + r)*66 + c  ->  global chunk
  // g = ((b*64 + ib*8 + kc)*66 + (y0+r))*66 + c ; per-ib advance 8*66*66 chunks
  const char* xTb = (const char*)xT;
  unsigned goff[9];
#pragma unroll
  for (int it = 0; it < 9; ++it) {
    int cid = tid + it * 256;
    int kc = cid / 264;
    int rem = cid - kc * 264;
    int r = rem / 66;
    int c = rem - r * 66;
    goff[it] = (unsigned)((((b * 64 + kc) * 66 + (y0 + r)) * 66 + c) * 16);
  }

  // A base for this wave's 64-o slice: ob = G*16 + wave*4 + p
  const short* wf0 = wfrag + ((size_t)((G * 16 + wave * 4) * 64 + lane)) * 8;

  for (int ib = 0; ib < 8; ++ib) {
    __syncthreads();
#pragma unroll
    for (int it = 0; it < 9; ++it) {
      int cid = tid + it * 256;
      if (cid < NCHUNK)
        load_lds_16(xTb + goff[it], xs + (size_t)cid * 8);
      goff[it] += 8 * 66 * 66 * 16;
    }
    __syncthreads();

#pragma unroll
    for (int kstep = 0; kstep < 2; ++kstep) {
      const int ib32 = ib * 2 + kstep;
#pragma unroll
      for (int t = 0; t < 9; ++t) {
        const int dy = t / 3 - 1;
        const int dx = t % 3 - 1;
        const short* wp = wf0 + (size_t)(t * 16 + ib32) * 16384;
        bf16x8 af[4];
#pragma unroll
        for (int p = 0; p < 4; ++p)
          af[p] = *(const bf16x8*)(wp + p * 512);
        const short* bp =
            xs + (((kstep * 4 + quad) * 4 + dy + 1) * 66 + 1 + n + dx) * 8;
        bf16x8 bf[8];
#pragma unroll
        for (int q = 0; q < 8; ++q)
          bf[q] = *(const bf16x8*)(bp + ((q >> 2) * 66 + (q & 3) * 16) * 8);
        __builtin_amdgcn_s_setprio(1);
#pragma unroll
        for (int p = 0; p < 4; ++p)
#pragma unroll
          for (int q = 0; q < 8; ++q)
            acc[p][q] = __builtin_amdgcn_mfma_f32_16x16x32_bf16(
                af[p], bf[q], acc[p][q], 0, 0, 0);
        __builtin_amdgcn_s_setprio(0);
      }
    }
  }

  // epilogue: demod, noise, bias, leaky
  const float sn = scale_noise[0];
#pragma unroll
  for (int q = 0; q < 8; ++q) {
    const int y = y0 + (q >> 2);
    const int col = (q & 3) * 16 + n;
    const float nz = sn * noise[b * HWSZ + y * 64 + col];
#pragma unroll
    for (int p = 0; p < 4; ++p) {
      const int o0 = G * 256 + wave * 64 + p * 16 + quad * 4;
#pragma unroll
      for (int r = 0; r < 4; ++r) {
        const int o = o0 + r;
        float v = fmaf(acc[p][q][r], demod[b * CC + o], nz + bias[o]);
        out[((size_t)(b * CC + o)) * HWSZ + y * 64 + col] =
            v > 0.f ? v : 0.2f * v;
      }
    }
  }
}

extern "C" void kernel_launch(void* const* d_in, const int* in_sizes, int n_in,
                              void* d_out, int out_size, void* d_ws, size_t ws_size,
                              hipStream_t stream) {
  const float* x     = (const float*)d_in[0];
  const float* w     = (const float*)d_in[1];
  const float* noise = (const float*)d_in[2];
  const float* cw    = (const float*)d_in[3];
  const float* sw    = (const float*)d_in[4];
  const float* sbias = (const float*)d_in[5];
  const float* bias  = (const float*)d_in[6];
  const float* sn    = (const float*)d_in[7];
  float* out = (float*)d_out;

  float* alpha = (float*)d_ws;                        // 4096 f
  float* demod = alpha + BB * CC;                     // 4096 f
  float* wsq   = demod + BB * CC;                     // 262144 f
  short* wfrag = (short*)(wsq + CC * CC);             // 9*16*32*64*8 = 2359296 bf16
  short* xT    = wfrag + (size_t)9 * 16 * 32 * 64 * 8;  // 8*64*66*66*8 bf16

  style_alpha_kernel<<<dim3(BB * CC / 4), 256, 0, stream>>>(w, sw, sbias, alpha);
  wprep_kernel<<<dim3((CC * CC) / 256), 256, 0, stream>>>(cw, wfrag, wsq);
  demod_kernel<<<dim3(BB * CC / 4), 256, 0, stream>>>(alpha, wsq, demod);
  xprep_kernel<<<dim3(66, 16, BB), 256, 0, stream>>>(x, alpha, xT);
  conv_kernel<<<dim3(32, 2, BB), 256, 0, stream>>>(
      xT, wfrag, noise, bias, sn, demod, out);
}